// Round 4
// baseline (202.923 us; speedup 1.0000x reference)
//
#include <hip/hip_runtime.h>
#include <hip/hip_bf16.h>
#include <stdint.h>
#include <stddef.h>

// GlobalLSTMCell — f32 in/out, bf16 MFMA compute.
//   ifo = sigmoid(x@W_ifo_x + b_ifo_x + h@W_ifo_h + b_ifo_h); i,f,o = split
//   a   = tanh(x@W_b_x + b_b_x + h@W_b_h + b_b_h)
//   c   = i*a + f*c_prev ; h = o*tanh(c) ; out = [h ; c] f32.
// R7: R6's asm lgkmcnt(0) drained LDS before every MFMA cluster -> read-burst
//     and MFMA-burst strictly alternated (5753 cyc/K-tile = sum of both).
//     Now: A-frag reads issued ONE PHASE EARLY into alternating aaA/aaB
//     buffers; bb read at consuming-phase head (pinned oldest via
//     sched_barrier so the compiler's auto wait is lgkmcnt(4), leaving the
//     next phase's reads in flight DURING the MFMA cluster). Manual lgkm
//     removed (compiler emits exact counted waits). vmcnt(4) at P2/P4/P6/P8
//     mid-phase; every read's staging confirmed by vmcnt+BAR before issue
//     (ledger verified for prologue/steady/tail).

#define BATCH 4096
#define FEAT  1024
#define HID   1024
#define NCAT  4096
#define KCAT  2048

typedef __attribute__((ext_vector_type(8))) __bf16 bf16x8;
typedef __attribute__((ext_vector_type(4))) float  floatx4;

__device__ __forceinline__ unsigned short f2bf(float f) {
    __hip_bfloat16 b = __float2bfloat16(f);
    return *reinterpret_cast<unsigned short*>(&b);
}
__device__ __forceinline__ void gl2lds16(const unsigned short* g, unsigned short* l) {
    __builtin_amdgcn_global_load_lds(
        (const __attribute__((address_space(1))) void*)g,
        (__attribute__((address_space(3))) void*)l, 16, 0, 0);
}

// ---------------- fused pack: Wt first, then Xcat ----------------
// blocks [0,2048):      weight transpose tile (heavy -> dispatch first).
// blocks [2048,3072):   Xcat[m][k] = bf16([x | h_prev][m][k]), 4 rows/block.
//   Virtual W_cat[k][q]: k<1024 x-weights else h-weights; q<3072 -> W_ifo (g=q>>10,
//   j=q&1023) else W_b (g=3, j=q-3072). Dest Wt[np][k], np=(j>>4)*64+g*16+(j&15).
#define TP_PAD 72   // u16 row stride; 144 B = 9*16 -> uint4-aligned rows, odd word shift
__global__ __launch_bounds__(256)
void pack_all(const float* __restrict__ x, const float* __restrict__ h,
              const float* __restrict__ Wix, const float* __restrict__ Wih,
              const float* __restrict__ Wbx, const float* __restrict__ Wbh,
              unsigned short* __restrict__ Xcat, unsigned short* __restrict__ Wt) {
    __shared__ unsigned short tile[64 * TP_PAD];
    const int t = threadIdx.x;
    const int b = blockIdx.x;
    if (b >= 2048) {
        // ---- xh part: 4 rows per block, 8 elems per thread per row ----
        const int mbase = (b - 2048) * 4;
#pragma unroll
        for (int r = 0; r < 4; ++r) {
            const int m = mbase + r;
            const float* src = (t < 128) ? (x + (size_t)m * FEAT + t * 8)
                                         : (h + (size_t)m * HID + (t - 128) * 8);
            float4 v0 = *(const float4*)src;
            float4 v1 = *(const float4*)(src + 4);
            union { unsigned short s16[8]; uint4 v; } pk;
            pk.s16[0] = f2bf(v0.x); pk.s16[1] = f2bf(v0.y);
            pk.s16[2] = f2bf(v0.z); pk.s16[3] = f2bf(v0.w);
            pk.s16[4] = f2bf(v1.x); pk.s16[5] = f2bf(v1.y);
            pk.s16[6] = f2bf(v1.z); pk.s16[7] = f2bf(v1.w);
            *(uint4*)(Xcat + (size_t)m * KCAT + t * 8) = pk.v;
        }
        return;
    }
    // ---- wt part: 64x64 tile transpose ----
    const int tid = b;
    const int k0  = (tid & 31) * 64;
    const int q0  = (tid >> 5) * 64;
    const float* src; int stride, cb;
    if (q0 < 3072) { src = (k0 < FEAT) ? Wix : Wih; stride = 3072; cb = q0; }
    else           { src = (k0 < FEAT) ? Wbx : Wbh; stride = 1024; cb = q0 - 3072; }
    const int krow = (k0 < FEAT) ? k0 : (k0 - FEAT);
    {   // load 64x64 (k x q) coalesced on q, cvt bf16, vector LDS stores
        int kl = t >> 2;
        int c0 = (t & 3) * 16;
        const float* s = src + (size_t)(krow + kl) * stride + cb + c0;
        union { unsigned short s16[16]; uint4 v[2]; } tmp;
#pragma unroll
        for (int u = 0; u < 16; u += 4) {
            float4 v = *(const float4*)(s + u);
            tmp.s16[u + 0] = f2bf(v.x); tmp.s16[u + 1] = f2bf(v.y);
            tmp.s16[u + 2] = f2bf(v.z); tmp.s16[u + 3] = f2bf(v.w);
        }
        *(uint4*)&tile[kl * TP_PAD + c0]     = tmp.v[0];
        *(uint4*)&tile[kl * TP_PAD + c0 + 8] = tmp.v[1];
    }
    __syncthreads();
    {   // transpose out: thread = (q-col nl, k-chunk seg)
        int nl = t >> 2, seg = t & 3;
        int q = q0 + nl;
        int g, j;
        if (q < 3072) { g = q >> 10; j = q & 1023; }
        else          { g = 3;       j = q - 3072; }
        int np = ((j >> 4) << 6) + (g << 4) + (j & 15);
        union { unsigned short s16[16]; uint4 v[2]; } pk;
#pragma unroll
        for (int u = 0; u < 16; ++u)
            pk.s16[u] = tile[(seg * 16 + u) * TP_PAD + nl];
        uint4* dst = (uint4*)(Wt + (size_t)np * KCAT + k0 + seg * 16);
        dst[0] = pk.v[0];
        dst[1] = pk.v[1];
    }
}

// ---------------- fused GEMM + LSTM epilogue (256x256, BK=64, 8-phase) ----------------
#define BM 256
#define BN 256
#define BK 64
#define NIT 16         // 16 iterations x 2 K-tiles = KCAT/BK = 32
#define HALF 8192      // u16 per half-region: 256 rows x 4 chunks x 8 u16 (16 KB)

// LDS: A(par,ks) at (par*2+ks)*HALF ; B(par,ks) at 32768 + (par*2+ks)*HALF.
#define A_OFF(PAR, KS) (((PAR) * 2 + (KS)) * HALF)
#define B_OFF(PAR, KS) (32768 + ((PAR) * 2 + (KS)) * HALF)

// Stage one half-tile (256 rows x 32 k) = 2 gl2lds/thread. LDS dest linear;
// T2 swizzle on the GLOBAL source chunk (chofs ^ (row>>1)&3), reads use same XOR.
__device__ __forceinline__ void stage_half(
    const unsigned short* __restrict__ src, int row0, int kt, int ks,
    unsigned short* __restrict__ ldsbase, int t) {
#pragma unroll
    for (int u = 0; u < 2; ++u) {
        int hslot = t + u * 512;               // 0..1023
        int row   = hslot >> 2;                // 0..255
        int chofs = hslot & 3;                 // 16B chunk within K-half
        int c     = chofs ^ ((row >> 1) & 3);  // swizzled source chunk
        gl2lds16(src + (size_t)(row0 + row) * KCAT + kt * BK + ks * 32 + c * 8,
                 ldsbase + hslot * 8);
    }
}

#define LOAD_B(PAR, KS)                                                         \
    _Pragma("unroll")                                                           \
    for (int g = 0; g < 4; ++g)                                                 \
        bb[g] = *(const bf16x8*)&lds[B_OFF(PAR, KS) + (wn + g * 16 + lm) * 32 + cr];
#define LOAD_A(DST, PAR, KS, IQ)                                                \
    _Pragma("unroll")                                                           \
    for (int ii = 0; ii < 4; ++ii)                                              \
        DST[ii] = *(const bf16x8*)&lds[A_OFF(PAR, KS) + (wm + (IQ) * 64 + ii * 16 + lm) * 32 + cr];
#define MFMA_CL(SRC, IQ)                                                        \
    __builtin_amdgcn_s_setprio(1);                                              \
    _Pragma("unroll")                                                           \
    for (int ii = 0; ii < 4; ++ii)                                              \
        _Pragma("unroll")                                                       \
        for (int g = 0; g < 4; ++g)                                             \
            acc[(IQ) * 4 + ii][g] = __builtin_amdgcn_mfma_f32_16x16x32_bf16(    \
                SRC[ii], bb[g], acc[(IQ) * 4 + ii][g], 0, 0, 0);                \
    __builtin_amdgcn_s_setprio(0);
#define BAR __builtin_amdgcn_s_barrier();
#define SBAR __builtin_amdgcn_sched_barrier(0);

__global__ __launch_bounds__(512, 2)
void lstm_fused(const unsigned short* __restrict__ Xcat,
                const unsigned short* __restrict__ Wt,
                const float* __restrict__ c_prev,
                const float* __restrict__ bix, const float* __restrict__ bih,
                const float* __restrict__ bbx, const float* __restrict__ bbh,
                float* __restrict__ out_h, float* __restrict__ out_c) {
    __shared__ unsigned short lds[65536];       // 128 KiB
    const int t    = threadIdx.x;
    const int lane = t & 63;
    const int wid  = t >> 6;                    // 0..7
    const int wm   = (wid >> 2) * 128;          // M-half of block tile
    const int wn   = (wid & 3) * 64;            // N-quarter (one gate-group)
    const int m0   = blockIdx.y * BM;
    const int n0   = blockIdx.x * BN;
    const int lm   = lane & 15;
    const int lk   = lane >> 4;                 // chunk-within-half (c&3)
    const int cr   = (lk ^ ((lm >> 1) & 3)) * 8;  // swizzled read chunk (u16)

    floatx4 acc[8][4];
#pragma unroll
    for (int i = 0; i < 8; ++i)
#pragma unroll
        for (int g = 0; g < 4; ++g) acc[i][g] = (floatx4){0.f, 0.f, 0.f, 0.f};

    // ---- prologue: K0 (both halves) + K1-ks0 = 6 half-tiles, 12 loads ----
    stage_half(Xcat, m0, 0, 0, lds + A_OFF(0, 0), t);
    stage_half(Wt,   n0, 0, 0, lds + B_OFF(0, 0), t);
    stage_half(Xcat, m0, 0, 1, lds + A_OFF(0, 1), t);
    stage_half(Wt,   n0, 0, 1, lds + B_OFF(0, 1), t);
    stage_half(Xcat, m0, 1, 0, lds + A_OFF(1, 0), t);
    stage_half(Wt,   n0, 1, 0, lds + B_OFF(1, 0), t);
    asm volatile("s_waitcnt vmcnt(4)" ::: "memory");  // K0 + K1? -> A/B(0,*) landed
    BAR

    bf16x8 aaA[4], aaB[4], bb[4];
    LOAD_A(aaA, 0, 0, 0)                        // pre-read for P1

    for (int it = 0; it < NIT; ++it) {
        const int k1 = 2 * it + 1, k2 = 2 * it + 2, k3 = 2 * it + 3;
        const bool more = (it < NIT - 1);

        // P1: MFMA(even ks0, iq0) | pre: bb(0,0) [this], aaB(0,0,iq1) [next]
        LOAD_B(0, 0) SBAR LOAD_A(aaB, 0, 0, 1)
        stage_half(Xcat, m0, k1, 1, lds + A_OFF(1, 1), t);
        BAR MFMA_CL(aaA, 0) BAR
        // P2: MFMA(even ks0, iq1) | pre: aaA(0,1,iq0) | vmcnt
        LOAD_A(aaA, 0, 1, 0)
        stage_half(Wt, n0, k1, 1, lds + B_OFF(1, 1), t);
        asm volatile("s_waitcnt vmcnt(4)" ::: "memory");
        BAR MFMA_CL(aaB, 1) BAR
        // P3: MFMA(even ks1, iq0) | pre: bb(0,1), aaB(0,1,iq1)
        LOAD_B(0, 1) SBAR LOAD_A(aaB, 0, 1, 1)
        if (more) stage_half(Xcat, m0, k2, 0, lds + A_OFF(0, 0), t);
        BAR MFMA_CL(aaA, 0) BAR
        // P4: MFMA(even ks1, iq1) | pre: aaA(1,0,iq0) | vmcnt
        LOAD_A(aaA, 1, 0, 0)
        if (more) {
            stage_half(Wt, n0, k2, 0, lds + B_OFF(0, 0), t);
            asm volatile("s_waitcnt vmcnt(4)" ::: "memory");
        } else {
            asm volatile("s_waitcnt vmcnt(2)" ::: "memory");
        }
        BAR MFMA_CL(aaB, 1) BAR
        // P5: MFMA(odd ks0, iq0) | pre: bb(1,0), aaB(1,0,iq1)
        LOAD_B(1, 0) SBAR LOAD_A(aaB, 1, 0, 1)
        if (more) stage_half(Xcat, m0, k2, 1, lds + A_OFF(0, 1), t);
        BAR MFMA_CL(aaA, 0) BAR
        // P6: MFMA(odd ks0, iq1) | pre: aaA(1,1,iq0) | vmcnt
        LOAD_A(aaA, 1, 1, 0)
        if (more) {
            stage_half(Wt, n0, k2, 1, lds + B_OFF(0, 1), t);
            asm volatile("s_waitcnt vmcnt(4)" ::: "memory");
        } else {
            asm volatile("s_waitcnt vmcnt(0)" ::: "memory");
        }
        BAR MFMA_CL(aaB, 1) BAR
        // P7: MFMA(odd ks1, iq0) | pre: bb(1,1), aaB(1,1,iq1)
        LOAD_B(1, 1) SBAR LOAD_A(aaB, 1, 1, 1)
        if (more) stage_half(Xcat, m0, k3, 0, lds + A_OFF(1, 0), t);
        BAR MFMA_CL(aaA, 0) BAR
        // P8: MFMA(odd ks1, iq1) | pre: aaA(next 0,0,iq0) | vmcnt
        if (more) {
            stage_half(Wt, n0, k3, 0, lds + B_OFF(1, 0), t);
            asm volatile("s_waitcnt vmcnt(4)" ::: "memory");
            LOAD_A(aaA, 0, 0, 0)
        }
        BAR MFMA_CL(aaB, 1) BAR
    }

    // ---- LSTM epilogue ----
    // acc[idx][g][r]: m = m0 + wm + idx*16 + (lane>>4)*4 + r,
    //                 gate g at j = ((n0+wn)>>6)*16 + lm.
    const int j  = (((n0 + wn) >> 6) << 4) + lm;
    const float bi = bix[j]           + bih[j];
    const float bf = bix[HID + j]     + bih[HID + j];
    const float bo = bix[2 * HID + j] + bih[2 * HID + j];
    const float ba = bbx[j]           + bbh[j];
#pragma unroll
    for (int i = 0; i < 8; ++i) {
#pragma unroll
        for (int r = 0; r < 4; ++r) {
            int m = m0 + wm + i * 16 + (lk * 4) + r;
            float pi = acc[i][0][r] + bi;
            float pf = acc[i][1][r] + bf;
            float po = acc[i][2][r] + bo;
            float pa = acc[i][3][r] + ba;
            float ig = 1.f / (1.f + __expf(-pi));
            float fg = 1.f / (1.f + __expf(-pf));
            float og = 1.f / (1.f + __expf(-po));
            float av = 2.f / (1.f + __expf(-2.f * pa)) - 1.f;
            float cp = c_prev[(size_t)m * HID + j];
            float cv = ig * av + fg * cp;
            float hv = og * (2.f / (1.f + __expf(-2.f * cv)) - 1.f);
            out_h[(size_t)m * HID + j] = hv;
            out_c[(size_t)m * HID + j] = cv;
        }
    }
}

// ---------------- naive fallback (ws too small) ----------------
__global__ void naive_lstm(const float* __restrict__ x, const float* __restrict__ h,
                           const float* __restrict__ cvp,
                           const float* __restrict__ Wix, const float* __restrict__ bix,
                           const float* __restrict__ Wih, const float* __restrict__ bih,
                           const float* __restrict__ Wbx, const float* __restrict__ bbx,
                           const float* __restrict__ Wbh, const float* __restrict__ bbh,
                           float* __restrict__ out_h, float* __restrict__ out_c) {
    const int j = blockIdx.x * 256 + threadIdx.x;
    const int m = blockIdx.y;
    float ai = 0.f, af = 0.f, ao = 0.f, aa = 0.f;
    for (int k = 0; k < FEAT; ++k) {
        float xk = x[(size_t)m * FEAT + k];
        ai += xk * Wix[(size_t)k * 3072 + j];
        af += xk * Wix[(size_t)k * 3072 + HID + j];
        ao += xk * Wix[(size_t)k * 3072 + 2 * HID + j];
        aa += xk * Wbx[(size_t)k * HID + j];
    }
    for (int k = 0; k < HID; ++k) {
        float hk = h[(size_t)m * HID + k];
        ai += hk * Wih[(size_t)k * 3072 + j];
        af += hk * Wih[(size_t)k * 3072 + HID + j];
        ao += hk * Wih[(size_t)k * 3072 + 2 * HID + j];
        aa += hk * Wbh[(size_t)k * HID + j];
    }
    ai += bix[j] + bih[j];
    af += bix[HID + j] + bih[HID + j];
    ao += bix[2 * HID + j] + bih[2 * HID + j];
    aa += bbx[j] + bbh[j];
    float ig = 1.f / (1.f + __expf(-ai));
    float fg = 1.f / (1.f + __expf(-af));
    float og = 1.f / (1.f + __expf(-ao));
    float av = 2.f / (1.f + __expf(-2.f * aa)) - 1.f;
    float cp = cvp[(size_t)m * HID + j];
    float cc = ig * av + fg * cp;
    float hh = og * (2.f / (1.f + __expf(-2.f * cc)) - 1.f);
    out_h[(size_t)m * HID + j] = hh;
    out_c[(size_t)m * HID + j] = cc;
}

extern "C" void kernel_launch(void* const* d_in, const int* in_sizes, int n_in,
                              void* d_out, int out_size, void* d_ws, size_t ws_size,
                              hipStream_t stream) {
    const float* x   = (const float*)d_in[0];
    const float* h   = (const float*)d_in[1];
    const float* c   = (const float*)d_in[2];
    const float* Wix = (const float*)d_in[3];
    const float* bix = (const float*)d_in[4];
    const float* Wih = (const float*)d_in[5];
    const float* bih = (const float*)d_in[6];
    const float* Wbx = (const float*)d_in[7];
    const float* bbx = (const float*)d_in[8];
    const float* Wbh = (const float*)d_in[9];
    const float* bbh = (const float*)d_in[10];

    float* out_h = (float*)d_out;
    float* out_c = out_h + (size_t)BATCH * HID;

    const size_t WT_BYTES = (size_t)NCAT * KCAT * 2;    // 16 MiB
    const size_t XC_BYTES = (size_t)BATCH * KCAT * 2;   // 16 MiB
    if (ws_size >= WT_BYTES + XC_BYTES) {
        unsigned short* Wt   = (unsigned short*)d_ws;
        unsigned short* Xcat = (unsigned short*)((char*)d_ws + WT_BYTES);
        pack_all<<<2048 + 1024, 256, 0, stream>>>(x, h, Wix, Wih, Wbx, Wbh, Xcat, Wt);
        lstm_fused<<<dim3(NCAT / BN, BATCH / BM), 512, 0, stream>>>(
            Xcat, Wt, c, bix, bih, bbx, bbh, out_h, out_c);
    } else {
        naive_lstm<<<dim3(HID / 256, BATCH), 256, 0, stream>>>(
            x, h, c, Wix, bix, Wih, bih, Wbx, bbx, Wbh, bbh, out_h, out_c);
    }
}

// Round 5
// 199.332 us; speedup vs baseline: 1.0180x; 1.0180x over previous
//
#include <hip/hip_runtime.h>
#include <hip/hip_bf16.h>
#include <stdint.h>
#include <stddef.h>

// GlobalLSTMCell — f32 in/out, bf16 MFMA compute.
//   ifo = sigmoid(x@W_ifo_x + b_ifo_x + h@W_ifo_h + b_ifo_h); i,f,o = split
//   a   = tanh(x@W_b_x + b_b_x + h@W_b_h + b_b_h)
//   c   = i*a + f*c_prev ; h = o*tanh(c) ; out = [h ; c] f32.
// R8: GEMM parked (R6/R7 schedule rounds neutral at 77 us; byte-identical
//     here as the A/B anchor). pack_all wt-transpose LDS fix: the 16 scalar
//     u16 reads/thread had a 4-way bank conflict each (72-u16 row stride:
//     36*16*seg = 0 mod 32 -> all 4 seg-groups alias 8 banks). Fix: XOR the
//     16-u16 chunk slot with (kl>>4) on write, un-XOR with (nl>>4)^seg on
//     read -> reads land on 4 disjoint 8-bank ranges, 2 lanes/word = free.
//     b128 writes stay 16B-aligned (chunk granularity 32B).

#define BATCH 4096
#define FEAT  1024
#define HID   1024
#define NCAT  4096
#define KCAT  2048

typedef __attribute__((ext_vector_type(8))) __bf16 bf16x8;
typedef __attribute__((ext_vector_type(4))) float  floatx4;

__device__ __forceinline__ unsigned short f2bf(float f) {
    __hip_bfloat16 b = __float2bfloat16(f);
    return *reinterpret_cast<unsigned short*>(&b);
}
__device__ __forceinline__ void gl2lds16(const unsigned short* g, unsigned short* l) {
    __builtin_amdgcn_global_load_lds(
        (const __attribute__((address_space(1))) void*)g,
        (__attribute__((address_space(3))) void*)l, 16, 0, 0);
}

// ---------------- fused pack: Wt first, then Xcat ----------------
// blocks [0,2048):      weight transpose tile (heavy -> dispatch first).
// blocks [2048,3072):   Xcat[m][k] = bf16([x | h_prev][m][k]), 4 rows/block.
//   Virtual W_cat[k][q]: k<1024 x-weights else h-weights; q<3072 -> W_ifo (g=q>>10,
//   j=q&1023) else W_b (g=3, j=q-3072). Dest Wt[np][k], np=(j>>4)*64+g*16+(j&15).
#define TP_PAD 72   // u16 row stride; 144 B = 9*16 -> 16B-aligned chunk slots
__global__ __launch_bounds__(256)
void pack_all(const float* __restrict__ x, const float* __restrict__ h,
              const float* __restrict__ Wix, const float* __restrict__ Wih,
              const float* __restrict__ Wbx, const float* __restrict__ Wbh,
              unsigned short* __restrict__ Xcat, unsigned short* __restrict__ Wt) {
    __shared__ unsigned short tile[64 * TP_PAD];
    const int t = threadIdx.x;
    const int b = blockIdx.x;
    if (b >= 2048) {
        // ---- xh part: 4 rows per block, 8 elems per thread per row ----
        const int mbase = (b - 2048) * 4;
#pragma unroll
        for (int r = 0; r < 4; ++r) {
            const int m = mbase + r;
            const float* src = (t < 128) ? (x + (size_t)m * FEAT + t * 8)
                                         : (h + (size_t)m * HID + (t - 128) * 8);
            float4 v0 = *(const float4*)src;
            float4 v1 = *(const float4*)(src + 4);
            union { unsigned short s16[8]; uint4 v; } pk;
            pk.s16[0] = f2bf(v0.x); pk.s16[1] = f2bf(v0.y);
            pk.s16[2] = f2bf(v0.z); pk.s16[3] = f2bf(v0.w);
            pk.s16[4] = f2bf(v1.x); pk.s16[5] = f2bf(v1.y);
            pk.s16[6] = f2bf(v1.z); pk.s16[7] = f2bf(v1.w);
            *(uint4*)(Xcat + (size_t)m * KCAT + t * 8) = pk.v;
        }
        return;
    }
    // ---- wt part: 64x64 tile transpose (chunk-XOR swizzled LDS) ----
    // tile element (k, q): stored at tile[k*72 + ((q>>4 ^ k>>4)<<4) + (q&15)].
    const int tid = b;
    const int k0  = (tid & 31) * 64;
    const int q0  = (tid >> 5) * 64;
    const float* src; int stride, cb;
    if (q0 < 3072) { src = (k0 < FEAT) ? Wix : Wih; stride = 3072; cb = q0; }
    else           { src = (k0 < FEAT) ? Wbx : Wbh; stride = 1024; cb = q0 - 3072; }
    const int krow = (k0 < FEAT) ? k0 : (k0 - FEAT);
    {   // load 64x64 (k x q) coalesced on q, cvt bf16, swizzled b128 LDS stores
        int kl = t >> 2;                       // k row 0..63
        int cc = t & 3;                        // q chunk 0..3 (16 u16)
        int c0s = ((cc ^ (kl >> 4)) << 4);     // swizzled chunk slot (16B-aligned x2)
        const float* s = src + (size_t)(krow + kl) * stride + cb + cc * 16;
        union { unsigned short s16[16]; uint4 v[2]; } tmp;
#pragma unroll
        for (int u = 0; u < 16; u += 4) {
            float4 v = *(const float4*)(s + u);
            tmp.s16[u + 0] = f2bf(v.x); tmp.s16[u + 1] = f2bf(v.y);
            tmp.s16[u + 2] = f2bf(v.z); tmp.s16[u + 3] = f2bf(v.w);
        }
        *(uint4*)&tile[kl * TP_PAD + c0s]     = tmp.v[0];
        *(uint4*)&tile[kl * TP_PAD + c0s + 8] = tmp.v[1];
    }
    __syncthreads();
    {   // transpose out: thread = (q-col nl, k-chunk seg); conflict-free reads
        int nl = t >> 2, seg = t & 3;
        int q = q0 + nl;
        int g, j;
        if (q < 3072) { g = q >> 10; j = q & 1023; }
        else          { g = 3;       j = q - 3072; }
        int np = ((j >> 4) << 6) + (g << 4) + (j & 15);
        // k = seg*16+u -> k>>4 == seg, so the un-XOR chunk is hoistable:
        int ccr = (((nl >> 4) ^ seg) << 4) + (nl & 15);
        union { unsigned short s16[16]; uint4 v[2]; } pk;
#pragma unroll
        for (int u = 0; u < 16; ++u)
            pk.s16[u] = tile[(seg * 16 + u) * TP_PAD + ccr];
        uint4* dst = (uint4*)(Wt + (size_t)np * KCAT + k0 + seg * 16);
        dst[0] = pk.v[0];
        dst[1] = pk.v[1];
    }
}

// ---------------- fused GEMM + LSTM epilogue (256x256, BK=64, 8-phase) ----------------
#define BM 256
#define BN 256
#define BK 64
#define NIT 16         // 16 iterations x 2 K-tiles = KCAT/BK = 32
#define HALF 8192      // u16 per half-region: 256 rows x 4 chunks x 8 u16 (16 KB)

// LDS: A(par,ks) at (par*2+ks)*HALF ; B(par,ks) at 32768 + (par*2+ks)*HALF.
#define A_OFF(PAR, KS) (((PAR) * 2 + (KS)) * HALF)
#define B_OFF(PAR, KS) (32768 + ((PAR) * 2 + (KS)) * HALF)

// Stage one half-tile (256 rows x 32 k) = 2 gl2lds/thread. LDS dest linear;
// T2 swizzle on the GLOBAL source chunk (chofs ^ (row>>1)&3), reads use same XOR.
__device__ __forceinline__ void stage_half(
    const unsigned short* __restrict__ src, int row0, int kt, int ks,
    unsigned short* __restrict__ ldsbase, int t) {
#pragma unroll
    for (int u = 0; u < 2; ++u) {
        int hslot = t + u * 512;               // 0..1023
        int row   = hslot >> 2;                // 0..255
        int chofs = hslot & 3;                 // 16B chunk within K-half
        int c     = chofs ^ ((row >> 1) & 3);  // swizzled source chunk
        gl2lds16(src + (size_t)(row0 + row) * KCAT + kt * BK + ks * 32 + c * 8,
                 ldsbase + hslot * 8);
    }
}

#define LOAD_B(PAR, KS)                                                         \
    _Pragma("unroll")                                                           \
    for (int g = 0; g < 4; ++g)                                                 \
        bb[g] = *(const bf16x8*)&lds[B_OFF(PAR, KS) + (wn + g * 16 + lm) * 32 + cr];
#define LOAD_A(DST, PAR, KS, IQ)                                                \
    _Pragma("unroll")                                                           \
    for (int ii = 0; ii < 4; ++ii)                                              \
        DST[ii] = *(const bf16x8*)&lds[A_OFF(PAR, KS) + (wm + (IQ) * 64 + ii * 16 + lm) * 32 + cr];
#define MFMA_CL(SRC, IQ)                                                        \
    __builtin_amdgcn_s_setprio(1);                                              \
    _Pragma("unroll")                                                           \
    for (int ii = 0; ii < 4; ++ii)                                              \
        _Pragma("unroll")                                                       \
        for (int g = 0; g < 4; ++g)                                             \
            acc[(IQ) * 4 + ii][g] = __builtin_amdgcn_mfma_f32_16x16x32_bf16(    \
                SRC[ii], bb[g], acc[(IQ) * 4 + ii][g], 0, 0, 0);                \
    __builtin_amdgcn_s_setprio(0);
#define BAR __builtin_amdgcn_s_barrier();
#define SBAR __builtin_amdgcn_sched_barrier(0);

__global__ __launch_bounds__(512, 2)
void lstm_fused(const unsigned short* __restrict__ Xcat,
                const unsigned short* __restrict__ Wt,
                const float* __restrict__ c_prev,
                const float* __restrict__ bix, const float* __restrict__ bih,
                const float* __restrict__ bbx, const float* __restrict__ bbh,
                float* __restrict__ out_h, float* __restrict__ out_c) {
    __shared__ unsigned short lds[65536];       // 128 KiB
    const int t    = threadIdx.x;
    const int lane = t & 63;
    const int wid  = t >> 6;                    // 0..7
    const int wm   = (wid >> 2) * 128;          // M-half of block tile
    const int wn   = (wid & 3) * 64;            // N-quarter (one gate-group)
    const int m0   = blockIdx.y * BM;
    const int n0   = blockIdx.x * BN;
    const int lm   = lane & 15;
    const int lk   = lane >> 4;                 // chunk-within-half (c&3)
    const int cr   = (lk ^ ((lm >> 1) & 3)) * 8;  // swizzled read chunk (u16)

    floatx4 acc[8][4];
#pragma unroll
    for (int i = 0; i < 8; ++i)
#pragma unroll
        for (int g = 0; g < 4; ++g) acc[i][g] = (floatx4){0.f, 0.f, 0.f, 0.f};

    // ---- prologue: K0 (both halves) + K1-ks0 = 6 half-tiles, 12 loads ----
    stage_half(Xcat, m0, 0, 0, lds + A_OFF(0, 0), t);
    stage_half(Wt,   n0, 0, 0, lds + B_OFF(0, 0), t);
    stage_half(Xcat, m0, 0, 1, lds + A_OFF(0, 1), t);
    stage_half(Wt,   n0, 0, 1, lds + B_OFF(0, 1), t);
    stage_half(Xcat, m0, 1, 0, lds + A_OFF(1, 0), t);
    stage_half(Wt,   n0, 1, 0, lds + B_OFF(1, 0), t);
    asm volatile("s_waitcnt vmcnt(4)" ::: "memory");  // A/B(0,*) landed
    BAR

    bf16x8 aaA[4], aaB[4], bb[4];
    LOAD_A(aaA, 0, 0, 0)                        // pre-read for P1

    for (int it = 0; it < NIT; ++it) {
        const int k1 = 2 * it + 1, k2 = 2 * it + 2, k3 = 2 * it + 3;
        const bool more = (it < NIT - 1);

        // P1: MFMA(even ks0, iq0) | pre: bb(0,0) [this], aaB(0,0,iq1) [next]
        LOAD_B(0, 0) SBAR LOAD_A(aaB, 0, 0, 1)
        stage_half(Xcat, m0, k1, 1, lds + A_OFF(1, 1), t);
        BAR MFMA_CL(aaA, 0) BAR
        // P2: MFMA(even ks0, iq1) | pre: aaA(0,1,iq0) | vmcnt
        LOAD_A(aaA, 0, 1, 0)
        stage_half(Wt, n0, k1, 1, lds + B_OFF(1, 1), t);
        asm volatile("s_waitcnt vmcnt(4)" ::: "memory");
        BAR MFMA_CL(aaB, 1) BAR
        // P3: MFMA(even ks1, iq0) | pre: bb(0,1), aaB(0,1,iq1)
        LOAD_B(0, 1) SBAR LOAD_A(aaB, 0, 1, 1)
        if (more) stage_half(Xcat, m0, k2, 0, lds + A_OFF(0, 0), t);
        BAR MFMA_CL(aaA, 0) BAR
        // P4: MFMA(even ks1, iq1) | pre: aaA(1,0,iq0) | vmcnt
        LOAD_A(aaA, 1, 0, 0)
        if (more) {
            stage_half(Wt, n0, k2, 0, lds + B_OFF(0, 0), t);
            asm volatile("s_waitcnt vmcnt(4)" ::: "memory");
        } else {
            asm volatile("s_waitcnt vmcnt(2)" ::: "memory");
        }
        BAR MFMA_CL(aaB, 1) BAR
        // P5: MFMA(odd ks0, iq0) | pre: bb(1,0), aaB(1,0,iq1)
        LOAD_B(1, 0) SBAR LOAD_A(aaB, 1, 0, 1)
        if (more) stage_half(Xcat, m0, k2, 1, lds + A_OFF(0, 1), t);
        BAR MFMA_CL(aaA, 0) BAR
        // P6: MFMA(odd ks0, iq1) | pre: aaA(1,1,iq0) | vmcnt
        LOAD_A(aaA, 1, 1, 0)
        if (more) {
            stage_half(Wt, n0, k2, 1, lds + B_OFF(0, 1), t);
            asm volatile("s_waitcnt vmcnt(4)" ::: "memory");
        } else {
            asm volatile("s_waitcnt vmcnt(0)" ::: "memory");
        }
        BAR MFMA_CL(aaB, 1) BAR
        // P7: MFMA(odd ks1, iq0) | pre: bb(1,1), aaB(1,1,iq1)
        LOAD_B(1, 1) SBAR LOAD_A(aaB, 1, 1, 1)
        if (more) stage_half(Xcat, m0, k3, 0, lds + A_OFF(1, 0), t);
        BAR MFMA_CL(aaA, 0) BAR
        // P8: MFMA(odd ks1, iq1) | pre: aaA(next 0,0,iq0) | vmcnt
        if (more) {
            stage_half(Wt, n0, k3, 0, lds + B_OFF(1, 0), t);
            asm volatile("s_waitcnt vmcnt(4)" ::: "memory");
            LOAD_A(aaA, 0, 0, 0)
        }
        BAR MFMA_CL(aaB, 1) BAR
    }

    // ---- LSTM epilogue ----
    // acc[idx][g][r]: m = m0 + wm + idx*16 + (lane>>4)*4 + r,
    //                 gate g at j = ((n0+wn)>>6)*16 + lm.
    const int j  = (((n0 + wn) >> 6) << 4) + lm;
    const float bi = bix[j]           + bih[j];
    const float bf = bix[HID + j]     + bih[HID + j];
    const float bo = bix[2 * HID + j] + bih[2 * HID + j];
    const float ba = bbx[j]           + bbh[j];
#pragma unroll
    for (int i = 0; i < 8; ++i) {
#pragma unroll
        for (int r = 0; r < 4; ++r) {
            int m = m0 + wm + i * 16 + (lk * 4) + r;
            float pi = acc[i][0][r] + bi;
            float pf = acc[i][1][r] + bf;
            float po = acc[i][2][r] + bo;
            float pa = acc[i][3][r] + ba;
            float ig = 1.f / (1.f + __expf(-pi));
            float fg = 1.f / (1.f + __expf(-pf));
            float og = 1.f / (1.f + __expf(-po));
            float av = 2.f / (1.f + __expf(-2.f * pa)) - 1.f;
            float cp = c_prev[(size_t)m * HID + j];
            float cv = ig * av + fg * cp;
            float hv = og * (2.f / (1.f + __expf(-2.f * cv)) - 1.f);
            out_h[(size_t)m * HID + j] = hv;
            out_c[(size_t)m * HID + j] = cv;
        }
    }
}

// ---------------- naive fallback (ws too small) ----------------
__global__ void naive_lstm(const float* __restrict__ x, const float* __restrict__ h,
                           const float* __restrict__ cvp,
                           const float* __restrict__ Wix, const float* __restrict__ bix,
                           const float* __restrict__ Wih, const float* __restrict__ bih,
                           const float* __restrict__ Wbx, const float* __restrict__ bbx,
                           const float* __restrict__ Wbh, const float* __restrict__ bbh,
                           float* __restrict__ out_h, float* __restrict__ out_c) {
    const int j = blockIdx.x * 256 + threadIdx.x;
    const int m = blockIdx.y;
    float ai = 0.f, af = 0.f, ao = 0.f, aa = 0.f;
    for (int k = 0; k < FEAT; ++k) {
        float xk = x[(size_t)m * FEAT + k];
        ai += xk * Wix[(size_t)k * 3072 + j];
        af += xk * Wix[(size_t)k * 3072 + HID + j];
        ao += xk * Wix[(size_t)k * 3072 + 2 * HID + j];
        aa += xk * Wbx[(size_t)k * HID + j];
    }
    for (int k = 0; k < HID; ++k) {
        float hk = h[(size_t)m * HID + k];
        ai += hk * Wih[(size_t)k * 3072 + j];
        af += hk * Wih[(size_t)k * 3072 + HID + j];
        ao += hk * Wih[(size_t)k * 3072 + 2 * HID + j];
        aa += hk * Wbh[(size_t)k * HID + j];
    }
    ai += bix[j] + bih[j];
    af += bix[HID + j] + bih[HID + j];
    ao += bix[2 * HID + j] + bih[2 * HID + j];
    aa += bbx[j] + bbh[j];
    float ig = 1.f / (1.f + __expf(-ai));
    float fg = 1.f / (1.f + __expf(-af));
    float og = 1.f / (1.f + __expf(-ao));
    float av = 2.f / (1.f + __expf(-2.f * aa)) - 1.f;
    float cp = cvp[(size_t)m * HID + j];
    float cc = ig * av + fg * cp;
    float hh = og * (2.f / (1.f + __expf(-2.f * cc)) - 1.f);
    out_h[(size_t)m * HID + j] = hh;
    out_c[(size_t)m * HID + j] = cc;
}

extern "C" void kernel_launch(void* const* d_in, const int* in_sizes, int n_in,
                              void* d_out, int out_size, void* d_ws, size_t ws_size,
                              hipStream_t stream) {
    const float* x   = (const float*)d_in[0];
    const float* h   = (const float*)d_in[1];
    const float* c   = (const float*)d_in[2];
    const float* Wix = (const float*)d_in[3];
    const float* bix = (const float*)d_in[4];
    const float* Wih = (const float*)d_in[5];
    const float* bih = (const float*)d_in[6];
    const float* Wbx = (const float*)d_in[7];
    const float* bbx = (const float*)d_in[8];
    const float* Wbh = (const float*)d_in[9];
    const float* bbh = (const float*)d_in[10];

    float* out_h = (float*)d_out;
    float* out_c = out_h + (size_t)BATCH * HID;

    const size_t WT_BYTES = (size_t)NCAT * KCAT * 2;    // 16 MiB
    const size_t XC_BYTES = (size_t)BATCH * KCAT * 2;   // 16 MiB
    if (ws_size >= WT_BYTES + XC_BYTES) {
        unsigned short* Wt   = (unsigned short*)d_ws;
        unsigned short* Xcat = (unsigned short*)((char*)d_ws + WT_BYTES);
        pack_all<<<2048 + 1024, 256, 0, stream>>>(x, h, Wix, Wih, Wbx, Wbh, Xcat, Wt);
        lstm_fused<<<dim3(NCAT / BN, BATCH / BM), 512, 0, stream>>>(
            Xcat, Wt, c, bix, bih, bbx, bbh, out_h, out_c);
    } else {
        naive_lstm<<<dim3(HID / 256, BATCH), 256, 0, stream>>>(
            x, h, c, Wix, bix, Wih, bih, Wbx, bbx, Wbh, bbh, out_h, out_c);
    }
}